// Round 5
// baseline (68.575 us; speedup 1.0000x reference)
//
#include <hip/hip_runtime.h>
#include <hip/hip_fp16.h>

typedef _Float16 half8 __attribute__((ext_vector_type(8)));
typedef __fp16 cvt2_t __attribute__((ext_vector_type(2)));
typedef float f32x4 __attribute__((ext_vector_type(4)));

// ---------------- workspace layout (bytes) ----------------
// W0F: fragment-ordered w0 fp16: linear uint4 index = t*1024 + kf*512 + nf*64 + l
//      element e of lane l = w0[n=nf*16+(l&15)][k=t*64+kf*32+(l>>4)*8+e], zero-padded
#define W0F_UNITS (13 * 1024)              // uint4 units
#define W1F_OFF   (W0F_UNITS * 16)         // 212992
#define W1F_UNITS 512                      // kf*128 + nf*64 + l
#define SW_OFF    (W1F_OFF + W1F_UNITS * 16)  // 221184
// SW (fp32): w3[22*32] @0 | w5p[21][24] @2816B | w7p[10][24] @4832B | b3 @5792B | b5 @5888B

// ---------------- LDS (per 1-wave block) ----------------
// x-tile staging: 2 buffers of [32 r][64 k] fp16, byte = r*128 + ((8c)^((r&7)<<4))
#define L_XT   0        // 2 x 4096
#define L_H0   8192     // [32 r][128 c] half, byte = r*256 + (2c ^ ((r&7)<<4))  (8192 B)
#define L_H1   16384    // [32 r][32 c]  half, byte = r*64  + (2c ^ ((r&3)<<4))  (2048 B)
#define L_H3   0        // [32][25] f32 (3200 B)  -- overlays XT after main loop
#define L_H5   3200     // [32][25] f32 (3200 B)
#define L_OS   6400     // [320] f32 out staging (1280 B)
#define LDS_SZ 18432

// ============ prep: rearrange weights into fragment order ============
__global__ void prep_weights(const float* __restrict__ w0,
                             const float* __restrict__ w1,
                             const float* __restrict__ w3,
                             const float* __restrict__ b3,
                             const float* __restrict__ w5,
                             const float* __restrict__ b5,
                             const float* __restrict__ w7,
                             char* __restrict__ ws) {
  int tid = blockIdx.x * 256 + threadIdx.x;
  if (tid < W0F_UNITS) {
    int t  = tid >> 10;
    int kf = (tid >> 9) & 1;
    int nf = (tid >> 6) & 7;
    int l  = tid & 63;
    int n  = nf * 16 + (l & 15);
    int k0 = t * 64 + kf * 32 + (l >> 4) * 8;
    alignas(16) __half h[8];
#pragma unroll
    for (int e = 0; e < 8; e++) {
      int k = k0 + e;
      h[e] = __float2half((n < 124 && k < 784) ? w0[n * 784 + k] : 0.f);
    }
    *(uint4*)(ws + tid * 16) = *(const uint4*)h;
    return;
  }
  int r = tid - W0F_UNITS;
  if (r < W1F_UNITS) {
    int kf = r >> 7;
    int nf = (r >> 6) & 1;
    int l  = r & 63;
    int n  = nf * 16 + (l & 15);
    int k0 = kf * 32 + (l >> 4) * 8;
    alignas(16) __half h[8];
#pragma unroll
    for (int e = 0; e < 8; e++) {
      int k = k0 + e;
      h[e] = __float2half((k < 124) ? w1[n * 124 + k] : 0.f);
    }
    *(uint4*)(ws + W1F_OFF + r * 16) = *(const uint4*)h;
    return;
  }
  r -= W1F_UNITS;
  float* sw = (float*)(ws + SW_OFF);
  if (r < 704) { sw[r] = w3[r]; return; }                     // w3 [22][32]
  r -= 704;
  if (r < 504) {                                              // w5 [21][24]
    int n = r / 24, k = r % 24;
    sw[704 + r] = (k < 22) ? w5[n * 22 + k] : 0.f;
    return;
  }
  r -= 504;
  if (r < 240) {                                              // w7 [10][24]
    int n = r / 24, k = r % 24;
    sw[1208 + r] = (k < 21) ? w7[n * 21 + k] : 0.f;
    return;
  }
  r -= 240;
  if (r < 24) { sw[1448 + r] = (r < 22) ? b3[r] : 0.f; return; }
  r -= 24;
  if (r < 24) { sw[1472 + r] = (r < 21) ? b5[r] : 0.f; return; }
}

// ============ fused MLP: 1 wave = 32 rows, no barriers in hot loop ============
__global__ __launch_bounds__(64, 2) void fused_mlp(
    const float* __restrict__ x, const char* __restrict__ ws,
    float* __restrict__ out) {
  __shared__ alignas(16) char sm[LDS_SZ];
  const int l  = threadIdx.x;
  const int lr = l & 15;
  const int lg = l >> 4;
  const size_t row0 = (size_t)blockIdx.x * 32;

  // coalesced x base: instr i covers rows 4i..4i+3 fully (1 KB contiguous segs)
  const float* xcol = x + (row0 + lg) * 784 + lr * 4;

  // LDS staging addresses (bytes)
  const int wb0 = lg * 128 + ((lr * 8) ^ (lg << 4));   // write base, even i
  const int wb1 = wb0 ^ 64;                            // write base, odd i
  const int rb0 = lr * 128 + ((lg * 16) ^ ((lr & 7) << 4));          // kf=0
  const int rb1 = lr * 128 + ((64 + lg * 16) ^ ((lr & 7) << 4));     // kf=1

  f32x4 acc[2][8];
#pragma unroll
  for (int mf = 0; mf < 2; mf++)
#pragma unroll
    for (int nf = 0; nf < 8; nf++) acc[mf][nf] = f32x4{0.f, 0.f, 0.f, 0.f};

  const uint4* wf = (const uint4*)ws;

  f32x4 xr[8];
  half8 bfr[2][8];

  // coalesced nt loads of tile T (GUARD: tile 12 has only chunks lr<4 valid)
#define XLOAD(T, GUARD)                                                        \
  {                                                                            \
    const float* pt = xcol + (size_t)(T) * 64;                                 \
    _Pragma("unroll") for (int i = 0; i < 8; i++) {                            \
      if (!(GUARD) || lr < 4)                                                  \
        xr[i] = __builtin_nontemporal_load((const f32x4*)(pt + i * 3136));     \
      else                                                                     \
        xr[i] = f32x4{0.f, 0.f, 0.f, 0.f};                                     \
    }                                                                          \
  }

  // cvt fp32->fp16 and store staged tile into LDS buffer PAR (swizzled)
#define XSTORE(PAR)                                                            \
  {                                                                            \
    _Pragma("unroll") for (int i = 0; i < 8; i++) {                            \
      cvt2_t q0 = __builtin_amdgcn_cvt_pkrtz(xr[i][0], xr[i][1]);              \
      cvt2_t q1 = __builtin_amdgcn_cvt_pkrtz(xr[i][2], xr[i][3]);              \
      uint2 u;                                                                 \
      u.x = __builtin_bit_cast(unsigned, q0);                                  \
      u.y = __builtin_bit_cast(unsigned, q1);                                  \
      *(uint2*)(sm + L_XT + (PAR) * 4096 + ((i & 1) ? wb1 : wb0) + i * 512) =  \
          u;                                                                   \
    }                                                                          \
  }

#define BFLOAD(T)                                                              \
  _Pragma("unroll") for (int kf = 0; kf < 2; kf++)                             \
      _Pragma("unroll") for (int nf = 0; nf < 8; nf++)                         \
          bfr[kf][nf] = __builtin_bit_cast(                                    \
              half8, wf[(T) * 1024 + kf * 512 + nf * 64 + l]);

  // prologue: stage tile 0, prefetch bf(0)
  XLOAD(0, false)
  BFLOAD(0)
  XSTORE(0)

#pragma unroll
  for (int T = 0; T < 13; T++) {
    const int par = T & 1;
    if (T < 12) XLOAD(T + 1, (T + 1) == 12)   // x(T+1) in flight across MFMA
    {
      half8 af[2][2];
      af[0][0] = *(const half8*)(sm + L_XT + par * 4096 + rb0);
      af[1][0] = *(const half8*)(sm + L_XT + par * 4096 + rb0 + 2048);
      af[0][1] = *(const half8*)(sm + L_XT + par * 4096 + rb1);
      af[1][1] = *(const half8*)(sm + L_XT + par * 4096 + rb1 + 2048);
#pragma unroll
      for (int kf = 0; kf < 2; kf++)
#pragma unroll
        for (int mf = 0; mf < 2; mf++)
#pragma unroll
          for (int nf = 0; nf < 8; nf++)
            acc[mf][nf] = __builtin_amdgcn_mfma_f32_16x16x32_f16(
                af[mf][kf], bfr[kf][nf], acc[mf][nf], 0, 0, 0);
    }
    if (T < 12) {
      BFLOAD(T + 1)        // issued before the x(T+1) drain: stays in flight
      XSTORE(par ^ 1)      // waits x(T+1), cvt, stage for next iter
    }
  }

  // issue w1 fragment loads early (consumed in phase 2, hides L2 latency)
  half8 b1[4][2];
  {
    const uint4* w1f = (const uint4*)(ws + W1F_OFF);
#pragma unroll
    for (int kf = 0; kf < 4; kf++)
#pragma unroll
      for (int nf = 0; nf < 2; nf++)
        b1[kf][nf] = __builtin_bit_cast(half8, w1f[kf * 128 + nf * 64 + l]);
  }

  // ---- phase 1: h0 (fp32 acc, no activation) -> LDS fp16, swizzled ----
#pragma unroll
  for (int mf = 0; mf < 2; mf++)
#pragma unroll
    for (int nf = 0; nf < 8; nf++)
#pragma unroll
      for (int q = 0; q < 4; q++) {
        int rr = mf * 16 + lg * 4 + q;
        int cc = nf * 16 + lr;
        *(__half*)(sm + L_H0 + rr * 256 + ((2 * cc) ^ ((rr & 7) << 4))) =
            __float2half(acc[mf][nf][q]);
      }
  __syncthreads();   // 1-wave block: cheap

  // ---- phase 2: layer 1 (N=32, K=128pad) + relu -> h1 ----
  f32x4 acc1[2][2];
#pragma unroll
  for (int mf = 0; mf < 2; mf++) {
    acc1[mf][0] = f32x4{0.f, 0.f, 0.f, 0.f};
    acc1[mf][1] = f32x4{0.f, 0.f, 0.f, 0.f};
  }
#pragma unroll
  for (int kf = 0; kf < 4; kf++) {
    half8 a1[2];
#pragma unroll
    for (int mf = 0; mf < 2; mf++) {
      int rr = mf * 16 + lr;
      int cb = kf * 64 + lg * 16;   // byte offset of k-group
      a1[mf] = *(const half8*)(sm + L_H0 + rr * 256 + (cb ^ ((rr & 7) << 4)));
    }
#pragma unroll
    for (int mf = 0; mf < 2; mf++)
#pragma unroll
      for (int nf = 0; nf < 2; nf++)
        acc1[mf][nf] = __builtin_amdgcn_mfma_f32_16x16x32_f16(
            a1[mf], b1[kf][nf], acc1[mf][nf], 0, 0, 0);
  }
#pragma unroll
  for (int mf = 0; mf < 2; mf++)
#pragma unroll
    for (int nf = 0; nf < 2; nf++)
#pragma unroll
      for (int q = 0; q < 4; q++) {
        int rr = mf * 16 + lg * 4 + q;
        int cc = nf * 16 + lr;
        float v = fmaxf(acc1[mf][nf][q], 0.f);
        *(__half*)(sm + L_H1 + rr * 64 + ((2 * cc) ^ ((rr & 3) << 4))) =
            __float2half(v);
      }
  __syncthreads();

  // ---- phase 3: layers 3,5,7 + log_softmax (fp32, 2 lanes per row) ----
  const int r = l & 31;
  const int j = l >> 5;
  float h1v[32];
#pragma unroll
  for (int cb = 0; cb < 4; cb++) {
    half8 v = *(const half8*)(sm + L_H1 + r * 64 + ((cb * 16) ^ ((r & 3) << 4)));
#pragma unroll
    for (int e = 0; e < 8; e++) h1v[cb * 8 + e] = (float)v[e];
  }
  const float* w3g = (const float*)(ws + SW_OFF);
  const float* w5g = (const float*)(ws + SW_OFF + 2816);
  const float* w7g = (const float*)(ws + SW_OFF + 4832);
  const float* b3g = (const float*)(ws + SW_OFF + 5792);
  const float* b5g = (const float*)(ws + SW_OFF + 5888);
  float* h3l = (float*)(sm + L_H3);
  float* h5l = (float*)(sm + L_H5);

#pragma unroll
  for (int i = 0; i < 11; i++) {
    int n = j + 2 * i;
    float s = b3g[n];
    const float4* wrow = (const float4*)(w3g + n * 32);
#pragma unroll
    for (int kk = 0; kk < 8; kk++) {
      float4 wv = wrow[kk];
      s += h1v[4 * kk] * wv.x + h1v[4 * kk + 1] * wv.y +
           h1v[4 * kk + 2] * wv.z + h1v[4 * kk + 3] * wv.w;
    }
    h3l[r * 25 + n] = fmaxf(s, 0.f);
  }
  __syncthreads();
  float h3v[24];
#pragma unroll
  for (int k = 0; k < 24; k++) h3v[k] = (k < 22) ? h3l[r * 25 + k] : 0.f;
#pragma unroll
  for (int i = 0; i < 11; i++) {
    int n = j + 2 * i;
    if (n < 21) {
      float s = b5g[n];
      const float4* wrow = (const float4*)(w5g + n * 24);
#pragma unroll
      for (int kk = 0; kk < 6; kk++) {
        float4 wv = wrow[kk];
        s += h3v[4 * kk] * wv.x + h3v[4 * kk + 1] * wv.y +
             h3v[4 * kk + 2] * wv.z + h3v[4 * kk + 3] * wv.w;
      }
      h5l[r * 25 + n] = fmaxf(s, 0.f);
    }
  }
  __syncthreads();
  if (j == 0) {
    float h5v[24];
#pragma unroll
    for (int k = 0; k < 24; k++) h5v[k] = (k < 21) ? h5l[r * 25 + k] : 0.f;
    float lgt[10];
    float mx = -3.4e38f;
#pragma unroll
    for (int n = 0; n < 10; n++) {
      float s = 0.f;
      const float4* wrow = (const float4*)(w7g + n * 24);
#pragma unroll
      for (int kk = 0; kk < 6; kk++) {
        float4 wv = wrow[kk];
        s += h5v[4 * kk] * wv.x + h5v[4 * kk + 1] * wv.y +
             h5v[4 * kk + 2] * wv.z + h5v[4 * kk + 3] * wv.w;
      }
      lgt[n] = s;
      mx = fmaxf(mx, s);
    }
    float se = 0.f;
#pragma unroll
    for (int n = 0; n < 10; n++) se += __expf(lgt[n] - mx);
    const float lse = mx + __logf(se);
    float* os = (float*)(sm + L_OS);
#pragma unroll
    for (int n = 0; n < 10; n++) os[r * 10 + n] = lgt[n] - lse;
  }
  __syncthreads();
  {
    const float* os = (const float*)(sm + L_OS);
#pragma unroll
    for (int i = 0; i < 5; i++) out[row0 * 10 + i * 64 + l] = os[i * 64 + l];
  }
}

extern "C" void kernel_launch(void* const* d_in, const int* in_sizes, int n_in,
                              void* d_out, int out_size, void* d_ws, size_t ws_size,
                              hipStream_t stream) {
  const float* x  = (const float*)d_in[0];
  const float* w0 = (const float*)d_in[1];
  const float* w1 = (const float*)d_in[2];
  const float* w3 = (const float*)d_in[3];
  const float* b3 = (const float*)d_in[4];
  const float* w5 = (const float*)d_in[5];
  const float* b5 = (const float*)d_in[6];
  const float* w7 = (const float*)d_in[7];
  float* out = (float*)d_out;
  char* ws = (char*)d_ws;

  const int prep_threads = W0F_UNITS + W1F_UNITS + 704 + 504 + 240 + 24 + 24;
  prep_weights<<<(prep_threads + 255) / 256, 256, 0, stream>>>(w0, w1, w3, b3,
                                                               w5, b5, w7, ws);
  fused_mlp<<<65536 / 32, 64, 0, stream>>>(x, ws, out);
}

// Round 6
// 57.618 us; speedup vs baseline: 1.1902x; 1.1902x over previous
//
#include <hip/hip_runtime.h>
#include <hip/hip_fp16.h>

typedef _Float16 half8 __attribute__((ext_vector_type(8)));
typedef __fp16 cvt2_t __attribute__((ext_vector_type(2)));
typedef float f32x4 __attribute__((ext_vector_type(4)));

// ---------------- workspace layout (bytes) ----------------
// W0F: fragment-ordered w0 fp16: linear uint4 index = t*1024 + kf*512 + nf*64 + l
//      element e of lane l = w0[n=nf*16+(l&15)][k=t*64+kf*32+(l>>4)*8+e], zero-padded
#define W0F_UNITS (13 * 1024)              // uint4 units
#define W1F_OFF   (W0F_UNITS * 16)         // 212992
#define W1F_UNITS 512                      // kf*128 + nf*64 + l
#define SW_OFF    (W1F_OFF + W1F_UNITS * 16)  // 221184
// SW (fp32): w3[22*32] @0 | w5p[21][24] @2816B | w7p[10][24] @4832B | b3 @5792B | b5 @5888B

// ---------------- LDS (per 1-wave block) ----------------
#define L_H0   0        // [32 r][128 c] half, byte = r*256 + (2c ^ ((r&7)<<4))  (8192 B)
#define L_H1   8192     // [32 r][32 c]  half, byte = r*64  + (2c ^ ((r&3)<<4))  (2048 B)
#define L_H3   0        // [32][25] f32 (3200 B)  -- overlays H0 after main loop
#define L_H5   3200     // [32][25] f32 (3200 B)
#define L_OS   6400     // [320] f32 out staging (1280 B)
#define LDS_SZ 10240

// ============ prep: rearrange weights into fragment order ============
__global__ void prep_weights(const float* __restrict__ w0,
                             const float* __restrict__ w1,
                             const float* __restrict__ w3,
                             const float* __restrict__ b3,
                             const float* __restrict__ w5,
                             const float* __restrict__ b5,
                             const float* __restrict__ w7,
                             char* __restrict__ ws) {
  int tid = blockIdx.x * 256 + threadIdx.x;
  if (tid < W0F_UNITS) {
    int t  = tid >> 10;
    int kf = (tid >> 9) & 1;
    int nf = (tid >> 6) & 7;
    int l  = tid & 63;
    int n  = nf * 16 + (l & 15);
    int k0 = t * 64 + kf * 32 + (l >> 4) * 8;
    alignas(16) __half h[8];
#pragma unroll
    for (int e = 0; e < 8; e++) {
      int k = k0 + e;
      h[e] = __float2half((n < 124 && k < 784) ? w0[n * 784 + k] : 0.f);
    }
    *(uint4*)(ws + tid * 16) = *(const uint4*)h;
    return;
  }
  int r = tid - W0F_UNITS;
  if (r < W1F_UNITS) {
    int kf = r >> 7;
    int nf = (r >> 6) & 1;
    int l  = r & 63;
    int n  = nf * 16 + (l & 15);
    int k0 = kf * 32 + (l >> 4) * 8;
    alignas(16) __half h[8];
#pragma unroll
    for (int e = 0; e < 8; e++) {
      int k = k0 + e;
      h[e] = __float2half((k < 124) ? w1[n * 124 + k] : 0.f);
    }
    *(uint4*)(ws + W1F_OFF + r * 16) = *(const uint4*)h;
    return;
  }
  r -= W1F_UNITS;
  float* sw = (float*)(ws + SW_OFF);
  if (r < 704) { sw[r] = w3[r]; return; }                     // w3 [22][32]
  r -= 704;
  if (r < 504) {                                              // w5 [21][24]
    int n = r / 24, k = r % 24;
    sw[704 + r] = (k < 22) ? w5[n * 22 + k] : 0.f;
    return;
  }
  r -= 504;
  if (r < 240) {                                              // w7 [10][24]
    int n = r / 24, k = r % 24;
    sw[1208 + r] = (k < 21) ? w7[n * 21 + k] : 0.f;
    return;
  }
  r -= 240;
  if (r < 24) { sw[1448 + r] = (r < 22) ? b3[r] : 0.f; return; }
  r -= 24;
  if (r < 24) { sw[1472 + r] = (r < 21) ? b5[r] : 0.f; return; }
}

// ============ fused MLP: 1 wave = 32 rows, no barriers, depth-2 x pipeline ====
__device__ __forceinline__ half8 cvt8(const f32x4& a, const f32x4& b) {
  cvt2_t p0 = __builtin_amdgcn_cvt_pkrtz(a[0], a[1]);
  cvt2_t p1 = __builtin_amdgcn_cvt_pkrtz(a[2], a[3]);
  cvt2_t p2 = __builtin_amdgcn_cvt_pkrtz(b[0], b[1]);
  cvt2_t p3 = __builtin_amdgcn_cvt_pkrtz(b[2], b[3]);
  uint4 u;
  u.x = __builtin_bit_cast(unsigned, p0);
  u.y = __builtin_bit_cast(unsigned, p1);
  u.z = __builtin_bit_cast(unsigned, p2);
  u.w = __builtin_bit_cast(unsigned, p3);
  return __builtin_bit_cast(half8, u);
}

__global__ __launch_bounds__(64, 2) void fused_mlp(
    const float* __restrict__ x, const char* __restrict__ ws,
    float* __restrict__ out) {
  __shared__ alignas(16) char sm[LDS_SZ];
  const int l  = threadIdx.x;
  const int lr = l & 15;
  const int lg = l >> 4;
  const size_t row0 = (size_t)blockIdx.x * 32;

  const float* xb0 = x + (row0 + lr) * 784;
  const float* xb1 = xb0 + 16 * 784;

  f32x4 acc[2][8];
#pragma unroll
  for (int mf = 0; mf < 2; mf++)
#pragma unroll
    for (int nf = 0; nf < 8; nf++) acc[mf][nf] = f32x4{0.f, 0.f, 0.f, 0.f};

  const uint4* wf = (const uint4*)ws;

  f32x4 xP[2][2][2], xQ[2][2][2];   // [mf][kf][h] raw fp32, ping-pong depth-2
  half8 bfr[2][8];

  // load tile T into buffer B. G=1: partial tile 12 (only kf==0 && lg<2 valid)
#define XLOAD(T, B, G)                                                         \
  {                                                                            \
    _Pragma("unroll") for (int mf = 0; mf < 2; mf++)                           \
        _Pragma("unroll") for (int kf = 0; kf < 2; kf++) {                     \
      const float* p = (mf ? xb1 : xb0) + (T) * 64 + kf * 32 + lg * 8;         \
      if (!(G) || (kf == 0 && lg < 2)) {                                       \
        B[mf][kf][0] = *(const f32x4*)p;                                       \
        B[mf][kf][1] = *(const f32x4*)(p + 4);                                 \
      } else {                                                                 \
        B[mf][kf][0] = f32x4{0.f, 0.f, 0.f, 0.f};                              \
        B[mf][kf][1] = f32x4{0.f, 0.f, 0.f, 0.f};                              \
      }                                                                        \
    }                                                                          \
  }

#define BF(T)                                                                  \
  _Pragma("unroll") for (int kf = 0; kf < 2; kf++)                             \
      _Pragma("unroll") for (int nf = 0; nf < 8; nf++)                         \
          bfr[kf][nf] = __builtin_bit_cast(                                    \
              half8, wf[(T) * 1024 + kf * 512 + nf * 64 + l]);

  // cvt(T) then MFMA(T). Waits: cvt -> x(T) (2-body slack); MFMA -> bf(T)
  // (1-body slack); both waits keep the younger x-prefetch in flight.
#define BODY(B)                                                                \
  {                                                                            \
    half8 af[2][2];                                                            \
    _Pragma("unroll") for (int mf = 0; mf < 2; mf++)                           \
        _Pragma("unroll") for (int kf = 0; kf < 2; kf++)                       \
            af[mf][kf] = cvt8(B[mf][kf][0], B[mf][kf][1]);                     \
    _Pragma("unroll") for (int kf = 0; kf < 2; kf++)                           \
        _Pragma("unroll") for (int mf = 0; mf < 2; mf++)                       \
            _Pragma("unroll") for (int nf = 0; nf < 8; nf++)                   \
                acc[mf][nf] = __builtin_amdgcn_mfma_f32_16x16x32_f16(          \
                    af[mf][kf], bfr[kf][nf], acc[mf][nf], 0, 0, 0);            \
  }

  // prologue: x(0), bf(0), x(1) — bf(0) issued before x(1) so its wait
  // keeps x(1) in flight.
  XLOAD(0, xP, 0)
  BF(0)
  XLOAD(1, xQ, 0)

  BODY(xP) BF(1)  XLOAD(2, xP, 0)
  BODY(xQ) BF(2)  XLOAD(3, xQ, 0)
  BODY(xP) BF(3)  XLOAD(4, xP, 0)
  BODY(xQ) BF(4)  XLOAD(5, xQ, 0)
  BODY(xP) BF(5)  XLOAD(6, xP, 0)
  BODY(xQ) BF(6)  XLOAD(7, xQ, 0)
  BODY(xP) BF(7)  XLOAD(8, xP, 0)
  BODY(xQ) BF(8)  XLOAD(9, xQ, 0)
  BODY(xP) BF(9)  XLOAD(10, xP, 0)
  BODY(xQ) BF(10) XLOAD(11, xQ, 0)
  BODY(xP) BF(11) XLOAD(12, xP, 1)   // tile 12 partial, zero-filled
  BODY(xQ) BF(12)
  BODY(xP)                            // tile 12 (zeros beyond k=784)

  // issue w1 fragment loads early (consumed in phase 2, hides L2 latency)
  half8 b1[4][2];
  {
    const uint4* w1f = (const uint4*)(ws + W1F_OFF);
#pragma unroll
    for (int kf = 0; kf < 4; kf++)
#pragma unroll
      for (int nf = 0; nf < 2; nf++)
        b1[kf][nf] = __builtin_bit_cast(half8, w1f[kf * 128 + nf * 64 + l]);
  }

  // ---- phase 1: h0 (fp32 acc, no activation) -> LDS fp16, swizzled ----
#pragma unroll
  for (int mf = 0; mf < 2; mf++)
#pragma unroll
    for (int nf = 0; nf < 8; nf++)
#pragma unroll
      for (int q = 0; q < 4; q++) {
        int rr = mf * 16 + lg * 4 + q;
        int cc = nf * 16 + lr;
        *(__half*)(sm + L_H0 + rr * 256 + ((2 * cc) ^ ((rr & 7) << 4))) =
            __float2half(acc[mf][nf][q]);
      }
  __syncthreads();   // 1-wave block: cheap

  // ---- phase 2: layer 1 (N=32, K=128pad) + relu -> h1 ----
  f32x4 acc1[2][2];
#pragma unroll
  for (int mf = 0; mf < 2; mf++) {
    acc1[mf][0] = f32x4{0.f, 0.f, 0.f, 0.f};
    acc1[mf][1] = f32x4{0.f, 0.f, 0.f, 0.f};
  }
#pragma unroll
  for (int kf = 0; kf < 4; kf++) {
    half8 a1[2];
#pragma unroll
    for (int mf = 0; mf < 2; mf++) {
      int rr = mf * 16 + lr;
      int cb = kf * 64 + lg * 16;   // byte offset of k-group
      a1[mf] = *(const half8*)(sm + L_H0 + rr * 256 + (cb ^ ((rr & 7) << 4)));
    }
#pragma unroll
    for (int mf = 0; mf < 2; mf++)
#pragma unroll
      for (int nf = 0; nf < 2; nf++)
        acc1[mf][nf] = __builtin_amdgcn_mfma_f32_16x16x32_f16(
            a1[mf], b1[kf][nf], acc1[mf][nf], 0, 0, 0);
  }
#pragma unroll
  for (int mf = 0; mf < 2; mf++)
#pragma unroll
    for (int nf = 0; nf < 2; nf++)
#pragma unroll
      for (int q = 0; q < 4; q++) {
        int rr = mf * 16 + lg * 4 + q;
        int cc = nf * 16 + lr;
        float v = fmaxf(acc1[mf][nf][q], 0.f);
        *(__half*)(sm + L_H1 + rr * 64 + ((2 * cc) ^ ((rr & 3) << 4))) =
            __float2half(v);
      }
  __syncthreads();

  // ---- phase 3: layers 3,5,7 + log_softmax (fp32, 2 lanes per row) ----
  const int r = l & 31;
  const int j = l >> 5;
  float h1v[32];
#pragma unroll
  for (int cb = 0; cb < 4; cb++) {
    half8 v = *(const half8*)(sm + L_H1 + r * 64 + ((cb * 16) ^ ((r & 3) << 4)));
#pragma unroll
    for (int e = 0; e < 8; e++) h1v[cb * 8 + e] = (float)v[e];
  }
  const float* w3g = (const float*)(ws + SW_OFF);
  const float* w5g = (const float*)(ws + SW_OFF + 2816);
  const float* w7g = (const float*)(ws + SW_OFF + 4832);
  const float* b3g = (const float*)(ws + SW_OFF + 5792);
  const float* b5g = (const float*)(ws + SW_OFF + 5888);
  float* h3l = (float*)(sm + L_H3);
  float* h5l = (float*)(sm + L_H5);

#pragma unroll
  for (int i = 0; i < 11; i++) {
    int n = j + 2 * i;
    float s = b3g[n];
    const float4* wrow = (const float4*)(w3g + n * 32);
#pragma unroll
    for (int kk = 0; kk < 8; kk++) {
      float4 wv = wrow[kk];
      s += h1v[4 * kk] * wv.x + h1v[4 * kk + 1] * wv.y +
           h1v[4 * kk + 2] * wv.z + h1v[4 * kk + 3] * wv.w;
    }
    h3l[r * 25 + n] = fmaxf(s, 0.f);
  }
  __syncthreads();
  float h3v[24];
#pragma unroll
  for (int k = 0; k < 24; k++) h3v[k] = (k < 22) ? h3l[r * 25 + k] : 0.f;
#pragma unroll
  for (int i = 0; i < 11; i++) {
    int n = j + 2 * i;
    if (n < 21) {
      float s = b5g[n];
      const float4* wrow = (const float4*)(w5g + n * 24);
#pragma unroll
      for (int kk = 0; kk < 6; kk++) {
        float4 wv = wrow[kk];
        s += h3v[4 * kk] * wv.x + h3v[4 * kk + 1] * wv.y +
             h3v[4 * kk + 2] * wv.z + h3v[4 * kk + 3] * wv.w;
      }
      h5l[r * 25 + n] = fmaxf(s, 0.f);
    }
  }
  __syncthreads();
  if (j == 0) {
    float h5v[24];
#pragma unroll
    for (int k = 0; k < 24; k++) h5v[k] = (k < 21) ? h5l[r * 25 + k] : 0.f;
    float lgt[10];
    float mx = -3.4e38f;
#pragma unroll
    for (int n = 0; n < 10; n++) {
      float s = 0.f;
      const float4* wrow = (const float4*)(w7g + n * 24);
#pragma unroll
      for (int kk = 0; kk < 6; kk++) {
        float4 wv = wrow[kk];
        s += h5v[4 * kk] * wv.x + h5v[4 * kk + 1] * wv.y +
             h5v[4 * kk + 2] * wv.z + h5v[4 * kk + 3] * wv.w;
      }
      lgt[n] = s;
      mx = fmaxf(mx, s);
    }
    float se = 0.f;
#pragma unroll
    for (int n = 0; n < 10; n++) se += __expf(lgt[n] - mx);
    const float lse = mx + __logf(se);
    float* os = (float*)(sm + L_OS);
#pragma unroll
    for (int n = 0; n < 10; n++) os[r * 10 + n] = lgt[n] - lse;
  }
  __syncthreads();
  {
    const float* os = (const float*)(sm + L_OS);
#pragma unroll
    for (int i = 0; i < 5; i++) out[row0 * 10 + i * 64 + l] = os[i * 64 + l];
  }
}

extern "C" void kernel_launch(void* const* d_in, const int* in_sizes, int n_in,
                              void* d_out, int out_size, void* d_ws, size_t ws_size,
                              hipStream_t stream) {
  const float* x  = (const float*)d_in[0];
  const float* w0 = (const float*)d_in[1];
  const float* w1 = (const float*)d_in[2];
  const float* w3 = (const float*)d_in[3];
  const float* b3 = (const float*)d_in[4];
  const float* w5 = (const float*)d_in[5];
  const float* b5 = (const float*)d_in[6];
  const float* w7 = (const float*)d_in[7];
  float* out = (float*)d_out;
  char* ws = (char*)d_ws;

  const int prep_threads = W0F_UNITS + W1F_UNITS + 704 + 504 + 240 + 24 + 24;
  prep_weights<<<(prep_threads + 255) / 256, 256, 0, stream>>>(w0, w1, w3, b3,
                                                               w5, b5, w7, ws);
  fused_mlp<<<65536 / 32, 64, 0, stream>>>(x, ws, out);
}